// Round 1
// baseline (404.833 us; speedup 1.0000x reference)
//
#include <hip/hip_runtime.h>
#include <math.h>

// 8388608 rows x 8 fp32. Memory-bound: 256 MB read + 32 MB write = 288 MB
// -> ~46 us at 6.3 TB/s. Compute (~6 trans + ~30 VALU per row) is ~3 us
// total across the chip - irrelevant.
//
// This version vs. previous (1 row/thread, 32768 blocks, scalar stores):
//  - grid capped at 2048 blocks (G11), grid-stride loop
//  - 4 rows per thread per iteration: 128 B contiguous per lane,
//    8x global_load_dwordx4 in flight per loop body (MLP)
//  - output packed into ONE dense float4 store per thread-iter
//    (was 1 dword/lane scatter)
//  - nontemporal load/store: pure streaming, no reuse, keep L2/L3 clean

typedef float v4f __attribute__((ext_vector_type(4)));

__device__ __forceinline__ float fast_rcp(float x) {
    return __builtin_amdgcn_rcpf(x);
}

// tanh(x) = sign(x) * (1 - 2e/(1+e)), e = exp(-2|x|).
// Large |x|: e underflows to 0 -> result +/-1 exactly. No branches.
__device__ __forceinline__ float fast_tanh(float x) {
    float a = fabsf(x);
    float e = __expf(-2.0f * a);          // v_mul + v_mul(log2e) + v_exp
    float r = fast_rcp(1.0f + e);         // v_add + v_rcp
    float t = __builtin_fmaf(-(e + e), r, 1.0f);
    return copysignf(t, x);               // 2 bit ops
}

// One row: a = {x0,x1,x2,x3}, b = {x4,x5,x6,x7}
__device__ __forceinline__ float row_expr(v4f a, v4f b) {
    float s   = __sinf(a[2]);                             // native v_sin
    float e3  = __expf(-fabsf(a[3]));                     // native v_exp
    float t1  = __builtin_fmaf(a[0], a[1], s) * e3;       // (x0*x1+sin x2)*exp(-|x3|)
    float den = __builtin_fmaf(b[1], b[1], __expf(b[2])); // x5^2 + exp(x6)
    float t2  = b[0] * fast_rcp(den);                     // x4 / den via v_rcp
    return fast_tanh(t1 + t2 - b[3]);
}

__global__ __launch_bounds__(256) void Expression_82643760709953_kernel(
    const v4f* __restrict__ in4, float* __restrict__ out, int n_rows) {
    const int tid = blockIdx.x * blockDim.x + threadIdx.x;
    const int nth = gridDim.x * blockDim.x;
    const int stride = 4 * nth;          // rows advanced per grid sweep

    int r = 4 * tid;
    // Main loop: 4 rows = 8 contiguous float4 loads (128 B/lane), 1 float4 store.
    for (; r + 3 < n_rows; r += stride) {
        const v4f* p = &in4[2 * r];
        v4f a0 = __builtin_nontemporal_load(&p[0]);
        v4f b0 = __builtin_nontemporal_load(&p[1]);
        v4f a1 = __builtin_nontemporal_load(&p[2]);
        v4f b1 = __builtin_nontemporal_load(&p[3]);
        v4f a2 = __builtin_nontemporal_load(&p[4]);
        v4f b2 = __builtin_nontemporal_load(&p[5]);
        v4f a3 = __builtin_nontemporal_load(&p[6]);
        v4f b3 = __builtin_nontemporal_load(&p[7]);
        v4f o;
        o[0] = row_expr(a0, b0);
        o[1] = row_expr(a1, b1);
        o[2] = row_expr(a2, b2);
        o[3] = row_expr(a3, b3);
        __builtin_nontemporal_store(o, (v4f*)&out[r]);   // dense 16 B store
    }
    // Tail: the (at most one) partial quad this thread owns. n_rows = 8388608
    // divides exactly at the bench shape, so this never executes there.
    if (r < n_rows) {
        for (int t = r; t < n_rows; ++t) {
            v4f a = __builtin_nontemporal_load(&in4[2 * t]);
            v4f b = __builtin_nontemporal_load(&in4[2 * t + 1]);
            out[t] = row_expr(a, b);
        }
    }
}

extern "C" void kernel_launch(void* const* d_in, const int* in_sizes, int n_in,
                              void* d_out, int out_size, void* d_ws, size_t ws_size,
                              hipStream_t stream) {
    const v4f* in4 = (const v4f*)d_in[0];
    float* out = (float*)d_out;
    int n_rows = out_size;  // 8388608
    int block = 256;
    // G11: cap grid, grid-stride the rest. 2048 blocks x 256 thr x 4 rows
    // = 2097152 rows/sweep -> exactly 4 sweeps at 8388608 rows.
    long quads = ((long)n_rows + 3) / 4;
    long need = (quads + block - 1) / block;
    int grid = (int)(need < 2048 ? need : 2048);
    if (grid < 1) grid = 1;
    Expression_82643760709953_kernel<<<grid, block, 0, stream>>>(in4, out, n_rows);
}

// Round 3
// 354.902 us; speedup vs baseline: 1.1407x; 1.1407x over previous
//
#include <hip/hip_runtime.h>
#include <math.h>

// 8388608 rows x 8 fp32. Memory-bound: 256 MB read + 32 MB write = 288 MB
// -> ~46 us at 6.3 TB/s. Harness fixed overhead ~245 us (1 GB poison fill etc).
//
// Round-2 change: PERFECT per-instruction coalescing. A wave processes 64
// contiguous rows (128 float4 = 2 KB) with two lane-contiguous float4 loads
// (each instr = one 1 KB segment, 8 cache lines -- the 6.3 TB/s copy pattern).
// Lane pairs then exchange one float4 via shfl_xor(1) (DPP quad-perm, no LDS)
// so every lane owns a full row:
//   even lane 2k: has a_k (self v0), gets b_k (partner's v0)  -> row k
//   odd  lane 2k+1: has b_{32+k} (self v1), gets a_{32+k}     -> row 32+k
// Stores: 64 dwords per wave inside one contiguous 256 B block (permuted
// within it -- coalesced). No nontemporal hints (round-1 regression).
// (Round-2 bench was an infra failure -- container died twice, no counters.
//  Exchange algebra re-verified; resubmitting verbatim.)

typedef float v4f __attribute__((ext_vector_type(4)));

__device__ __forceinline__ float fast_rcp(float x) {
    return __builtin_amdgcn_rcpf(x);
}

// tanh(x) = sign(x) * (1 - 2e/(1+e)), e = exp(-2|x|).
// Large |x|: e underflows to 0 -> result +/-1 exactly. No branches.
__device__ __forceinline__ float fast_tanh(float x) {
    float a = fabsf(x);
    float e = __expf(-2.0f * a);          // v_mul + v_mul(log2e) + v_exp
    float r = fast_rcp(1.0f + e);         // v_add + v_rcp
    float t = __builtin_fmaf(-(e + e), r, 1.0f);
    return copysignf(t, x);               // 2 bit ops
}

// One row: a = {x0,x1,x2,x3}, b = {x4,x5,x6,x7}
__device__ __forceinline__ float row_expr(v4f a, v4f b) {
    float s   = __sinf(a[2]);                             // native v_sin
    float e3  = __expf(-fabsf(a[3]));                     // native v_exp
    float t1  = __builtin_fmaf(a[0], a[1], s) * e3;       // (x0*x1+sin x2)*exp(-|x3|)
    float den = __builtin_fmaf(b[1], b[1], __expf(b[2])); // x5^2 + exp(x6)
    float t2  = b[0] * fast_rcp(den);                     // x4 / den via v_rcp
    return fast_tanh(t1 + t2 - b[3]);
}

__global__ __launch_bounds__(256) void Expression_82643760709953_kernel(
    const v4f* __restrict__ in4, float* __restrict__ out, int n_rows) {
    const int lane   = threadIdx.x & 63;
    const int wib    = threadIdx.x >> 6;                       // wave in block
    const long gwave = (long)blockIdx.x * (blockDim.x >> 6) + wib;
    const long nwave = (long)gridDim.x * (blockDim.x >> 6);
    const long nchunk = (long)n_rows >> 6;                     // 64-row chunks

    for (long c = gwave; c < nchunk; c += nwave) {
        const long b4 = c << 7;                 // chunk base, float4 units
        // Two perfectly lane-contiguous 16 B loads: 1 KB/instr per wave.
        v4f v0 = in4[b4 + lane];
        v4f v1 = in4[b4 + 64 + lane];
        // Pair exchange: even lane sends v1 (partner wants a_{32+k}),
        // odd lane sends v0 (partner wants b_k).
        v4f sel = (lane & 1) ? v0 : v1;
        v4f rcv;
        rcv[0] = __shfl_xor(sel[0], 1);
        rcv[1] = __shfl_xor(sel[1], 1);
        rcv[2] = __shfl_xor(sel[2], 1);
        rcv[3] = __shfl_xor(sel[3], 1);
        v4f a = (lane & 1) ? rcv : v0;          // row's x0..x3
        v4f b = (lane & 1) ? v1  : rcv;         // row's x4..x7
        long row = (c << 6) + ((long)(lane & 1) << 5) + (lane >> 1);
        out[row] = row_expr(a, b);
    }

    // Tail: rows beyond the last full 64-row chunk (never hit at 8388608).
    const long done = nchunk << 6;
    const long gtid = (long)blockIdx.x * blockDim.x + threadIdx.x;
    const long nthr = (long)gridDim.x * blockDim.x;
    for (long t = done + gtid; t < n_rows; t += nthr) {
        v4f a = in4[2 * t];
        v4f b = in4[2 * t + 1];
        out[t] = row_expr(a, b);
    }
}

extern "C" void kernel_launch(void* const* d_in, const int* in_sizes, int n_in,
                              void* d_out, int out_size, void* d_ws, size_t ws_size,
                              hipStream_t stream) {
    const v4f* in4 = (const v4f*)d_in[0];
    float* out = (float*)d_out;
    int n_rows = out_size;  // 8388608
    int block = 256;        // 4 waves/block
    // One 64-row chunk per wave, one pass: 131072 waves -> 32768 blocks
    // (round-0-proven grid scale; loop handles any shape).
    long nchunk = ((long)n_rows + 63) >> 6;
    long wpb = block >> 6;
    long need = (nchunk + wpb - 1) / wpb;
    int grid = (int)(need < 32768 ? need : 32768);
    if (grid < 1) grid = 1;
    Expression_82643760709953_kernel<<<grid, block, 0, stream>>>(in4, out, n_rows);
}